// Round 1
// baseline (173.975 us; speedup 1.0000x reference)
//
#include <hip/hip_runtime.h>
#include <hip/hip_bf16.h>

typedef short bfrag8 __attribute__((ext_vector_type(8)));
typedef float f32x4v __attribute__((ext_vector_type(4)));
typedef unsigned short U16;

// B=4, N=4096, D=128 fixed by the problem.
#define NN 4096
#define DD 128

static __device__ __forceinline__ U16 f2bf(float f){
  union { __hip_bfloat16 b; U16 u; } cv;
  cv.b = __float2bfloat16(f);
  return cv.u;
}

// ---------------- kernel 0: WT[dp][d] = bf16(W[d][dp]) ----------------
__global__ void k0_wt(const float* __restrict__ W, U16* __restrict__ WT){
  int i = blockIdx.x*256 + threadIdx.x;      // i = d*128 + dp
  int d = i >> 7, dp = i & 127;
  WT[dp*128 + d] = f2bf(W[i]);
}

// ---------------- kernel 1: x2 = x*(nw+1)+nb; h_raw = x2@W (MFMA bf16);
// LayerNorm -> h_ln (f32), hT (bf16 transposed), f1/f2 ----------------
__global__ __launch_bounds__(256) void k1_prep(
    const float* __restrict__ x, const U16* __restrict__ WT,
    const float* __restrict__ nw, const float* __restrict__ nb,
    const float* __restrict__ gamma, const float* __restrict__ beta,
    const float* __restrict__ a1, const float* __restrict__ a2,
    float* __restrict__ h_ln, U16* __restrict__ hT,
    float* __restrict__ f1, float* __restrict__ f2)
{
  __shared__ U16 lds[16384];                 // 32 KB: WT (swizzled), later hb[64][128]
  const int tid = threadIdx.x;
  const int lane = tid & 63, w = tid >> 6;
  const int l15 = lane & 15, grp = lane >> 4;

  // stage WT into LDS with XOR swizzle: row dp (256B), 16B chunk c:
  // byte = dp*256 + (c*16 ^ ((dp&15)<<4))  (ushort idx = dp*128 + (c*8 ^ ((dp&15)<<3)))
  #pragma unroll
  for (int q = 0; q < 8; ++q){
    int cid = q*256 + tid;
    int dp = cid >> 4, c = cid & 15;
    *reinterpret_cast<int4*>(lds + dp*128 + ((c*8) ^ ((dp&15)<<3))) =
        *reinterpret_cast<const int4*>(WT + cid*8);
  }
  __syncthreads();

  const int rA = blockIdx.x*64 + w*16 + l15; // global row for A operand
  const int nA = rA & 4095;
  const float wgt = nw[nA] + 1.0f, bia = nb[nA];
  const float* xr = x + (size_t)rA*DD;

  f32x4v acc[8] = {};
  #pragma unroll
  for (int ks = 0; ks < 4; ++ks){
    int d8 = ks*32 + grp*8;
    float4 xa = *reinterpret_cast<const float4*>(xr + d8);
    float4 xb = *reinterpret_cast<const float4*>(xr + d8 + 4);
    bfrag8 af;
    af[0] = (short)f2bf(xa.x*wgt + bia);
    af[1] = (short)f2bf(xa.y*wgt + bia);
    af[2] = (short)f2bf(xa.z*wgt + bia);
    af[3] = (short)f2bf(xa.w*wgt + bia);
    af[4] = (short)f2bf(xb.x*wgt + bia);
    af[5] = (short)f2bf(xb.y*wgt + bia);
    af[6] = (short)f2bf(xb.z*wgt + bia);
    af[7] = (short)f2bf(xb.w*wgt + bia);
    #pragma unroll
    for (int nf = 0; nf < 8; ++nf){
      int dp = nf*16 + l15;
      bfrag8 bf = *reinterpret_cast<const bfrag8*>(
          lds + dp*128 + ((((ks*4 + grp)*8)) ^ ((dp&15)<<3)));
      acc[nf] = __builtin_amdgcn_mfma_f32_16x16x32_bf16(af, bf, acc[nf], 0, 0, 0);
    }
  }

  float gc[8], bc[8], c1[8], c2[8];
  #pragma unroll
  for (int nf = 0; nf < 8; ++nf){
    int col = nf*16 + l15;
    gc[nf] = gamma[col]; bc[nf] = beta[col];
    c1[nf] = a1[col];    c2[nf] = a2[col];
  }

  // C/D layout: col = lane&15, row = (lane>>4)*4 + r   (m89-verified)
  const int rCb = blockIdx.x*64 + w*16 + grp*4;
  #pragma unroll
  for (int r = 0; r < 4; ++r){
    float s = 0.f, qq = 0.f;
    #pragma unroll
    for (int nf = 0; nf < 8; ++nf){ float v = acc[nf][r]; s += v; qq += v*v; }
    #pragma unroll
    for (int m = 1; m < 16; m <<= 1){ s += __shfl_xor(s, m); qq += __shfl_xor(qq, m); }
    float mu = s * 0.0078125f;
    float var = fmaxf(qq*0.0078125f - mu*mu, 0.f);
    float rstd = rsqrtf(var + 1e-5f);
    const int rC = rCb + r;
    float p1 = 0.f, p2 = 0.f;
    #pragma unroll
    for (int nf = 0; nf < 8; ++nf){
      float hn = (acc[nf][r] - mu)*rstd*gc[nf] + bc[nf];
      acc[nf][r] = hn;
      h_ln[(size_t)rC*DD + nf*16 + l15] = hn;
      p1 += hn*c1[nf]; p2 += hn*c2[nf];
    }
    #pragma unroll
    for (int m = 1; m < 16; m <<= 1){ p1 += __shfl_xor(p1, m); p2 += __shfl_xor(p2, m); }
    if (l15 == 0){ f1[rC] = p1; f2[rC] = p2; }
  }

  __syncthreads();   // everyone done reading WT; reuse LDS as hb[64][128]
  #pragma unroll
  for (int r = 0; r < 4; ++r)
    #pragma unroll
    for (int nf = 0; nf < 8; ++nf)
      lds[(w*16 + grp*4 + r)*128 + nf*16 + l15] = f2bf(acc[nf][r]);
  __syncthreads();

  // transposed write: hT[b][dp][n]
  {
    const int dp = tid >> 1, half = tid & 1;
    const int rGlob0 = blockIdx.x*64;
    const int bB = rGlob0 >> 12;
    const int n0 = (rGlob0 & 4095) + half*32;
    U16* dst = hT + ((size_t)bB*DD + dp)*NN + n0;
    #pragma unroll
    for (int k = 0; k < 4; ++k){
      bfrag8 t;
      #pragma unroll
      for (int e = 0; e < 8; ++e)
        t[e] = (short)lds[(half*32 + k*8 + e)*128 + dp];
      *reinterpret_cast<bfrag8*>(dst + k*8) = t;
    }
  }
}

// ---------------- kernel 2: fused att-gen + att@h + elu + residual ----------------
// grid 256: block = (batch b, 64 i-rows); 8 waves = 4 tiles(16 rows) x 2 K-halves.
__global__ __launch_bounds__(512) void k2_main(
    const int* __restrict__ adj, const U16* __restrict__ hT,
    const float* __restrict__ f1, const float* __restrict__ f2,
    const float* __restrict__ h_ln, float* __restrict__ out)
{
  __shared__ U16 tb[16384];                  // 2 K-half tiles [128][64] bf16, swizzled
  const int tid = threadIdx.x;
  const int lane = tid & 63, w = tid >> 6;
  const int kh = w & 1, tile = w >> 1;
  const int l15 = lane & 15, grp = lane >> 4;
  const int b = blockIdx.x >> 6;
  const int iblk = (blockIdx.x & 63) * 64;
  const int i0 = iblk + tile*16;
  const int row = i0 + l15;                  // this lane's score row

  const float CMASK = 0.2f * -9.0e15f;       // leaky(MASK_VAL), exact as reference
  const float A2C   = 0.2f * 0.2f;           // leaky∘leaky negative slope

  const float f1v = f1[b*NN + row];
  const float* f2b = f2 + b*NN;
  const int* adjr = adj + (size_t)row * NN;
  const U16* hTb = hT + (size_t)b * DD * NN;

  // staging map: 2048 16B chunks (2 tiles x 128 rows x 8 chunks), 4 per thread
  const U16* gq[4]; int lq[4];
  #pragma unroll
  for (int q = 0; q < 4; ++q){
    int cid = q*512 + tid;
    int khp = cid >> 10, d = (cid >> 3) & 127, c = cid & 7;
    gq[q] = hTb + (size_t)d*NN + khp*2048 + c*8;
    lq[q] = khp*8192 + d*64 + ((c*8) ^ ((d&7)<<3));   // ushort idx, XOR-swizzled
  }

  f32x4v acc[8] = {};
  int4 ld[4];
  #pragma unroll
  for (int q = 0; q < 4; ++q) ld[q] = *reinterpret_cast<const int4*>(gq[q]);

  for (int s = 0; s < 32; ++s){
    __syncthreads();                          // previous compute done
    #pragma unroll
    for (int q = 0; q < 4; ++q)
      *reinterpret_cast<int4*>(tb + lq[q]) = ld[q];
    __syncthreads();                          // tiles ready
    if (s + 1 < 32){                          // prefetch next step (hides HBM/L2)
      #pragma unroll
      for (int q = 0; q < 4; ++q)
        ld[q] = *reinterpret_cast<const int4*>(gq[q] + (s+1)*64);
    }
    #pragma unroll
    for (int kc = 0; kc < 2; ++kc){
      const int j0 = kh*2048 + s*64 + kc*32 + grp*8;
      float4 fa = *reinterpret_cast<const float4*>(f2b + j0);
      float4 fb = *reinterpret_cast<const float4*>(f2b + j0 + 4);
      int4 aa = *reinterpret_cast<const int4*>(adjr + j0);
      int4 ab = *reinterpret_cast<const int4*>(adjr + j0 + 4);
      bfrag8 af;
      { float sv, uv;
        sv = f1v + fa.x; uv = fmaxf(sv, A2C*sv); af[0] = (short)f2bf(aa.x > 0 ? uv : CMASK);
        sv = f1v + fa.y; uv = fmaxf(sv, A2C*sv); af[1] = (short)f2bf(aa.y > 0 ? uv : CMASK);
        sv = f1v + fa.z; uv = fmaxf(sv, A2C*sv); af[2] = (short)f2bf(aa.z > 0 ? uv : CMASK);
        sv = f1v + fa.w; uv = fmaxf(sv, A2C*sv); af[3] = (short)f2bf(aa.w > 0 ? uv : CMASK);
        sv = f1v + fb.x; uv = fmaxf(sv, A2C*sv); af[4] = (short)f2bf(ab.x > 0 ? uv : CMASK);
        sv = f1v + fb.y; uv = fmaxf(sv, A2C*sv); af[5] = (short)f2bf(ab.y > 0 ? uv : CMASK);
        sv = f1v + fb.z; uv = fmaxf(sv, A2C*sv); af[6] = (short)f2bf(ab.z > 0 ? uv : CMASK);
        sv = f1v + fb.w; uv = fmaxf(sv, A2C*sv); af[7] = (short)f2bf(ab.w > 0 ? uv : CMASK);
      }
      const int cr8 = (kc*4 + grp)*8;
      #pragma unroll
      for (int nf = 0; nf < 8; ++nf){
        int d = nf*16 + l15;
        bfrag8 bf = *reinterpret_cast<const bfrag8*>(
            tb + kh*8192 + d*64 + (cr8 ^ ((d&7)<<3)));
        acc[nf] = __builtin_amdgcn_mfma_f32_16x16x32_bf16(af, bf, acc[nf], 0, 0, 0);
      }
    }
  }

  // combine K-halves through LDS, then fused epilogue
  __syncthreads();
  float* sc = reinterpret_cast<float*>(tb);   // 8192 floats = 4 tiles x 16 x 128
  if (kh == 1){
    #pragma unroll
    for (int nf = 0; nf < 8; ++nf)
      #pragma unroll
      for (int r = 0; r < 4; ++r)
        sc[tile*2048 + (grp*4 + r)*128 + nf*16 + l15] = acc[nf][r];
  }
  __syncthreads();
  if (kh == 0){
    #pragma unroll
    for (int nf = 0; nf < 8; ++nf)
      #pragma unroll
      for (int r = 0; r < 4; ++r){
        float hp = acc[nf][r] + sc[tile*2048 + (grp*4 + r)*128 + nf*16 + l15];
        float e = hp > 0.f ? hp : __expf(hp) - 1.f;
        size_t o = ((size_t)b*NN + i0 + grp*4 + r)*DD + nf*16 + l15;
        out[o] = e + h_ln[o];
      }
  }
}

extern "C" void kernel_launch(void* const* d_in, const int* in_sizes, int n_in,
                              void* d_out, int out_size, void* d_ws, size_t ws_size,
                              hipStream_t stream) {
  const float* x     = (const float*)d_in[0];
  const int*   adj   = (const int*)  d_in[1];
  const float* W     = (const float*)d_in[2];
  const float* a1    = (const float*)d_in[3];
  const float* a2    = (const float*)d_in[4];
  const float* nw    = (const float*)d_in[5];
  const float* nb    = (const float*)d_in[6];
  const float* gamma = (const float*)d_in[7];
  const float* beta  = (const float*)d_in[8];
  float* out = (float*)d_out;

  char* ws = (char*)d_ws;
  float* h_ln = (float*)(ws);                        // 8 MB
  U16*   hT   = (U16*)  (ws + 8*1024*1024);          // 4 MB
  U16*   WT   = (U16*)  (ws + 12*1024*1024);         // 32 KB
  float* f1   = (float*)(ws + 12*1024*1024 + 64*1024);
  float* f2   = f1 + 4*NN;

  k0_wt <<<dim3(64),  dim3(256), 0, stream>>>(W, WT);
  k1_prep<<<dim3(256), dim3(256), 0, stream>>>(x, WT, nw, nb, gamma, beta, a1, a2,
                                               h_ln, hT, f1, f2);
  k2_main<<<dim3(256), dim3(512), 0, stream>>>(adj, hT, f1, f2, h_ln, out);
}

// Round 2
// 74.620 us; speedup vs baseline: 2.3315x; 2.3315x over previous
//
#include <hip/hip_runtime.h>
#include <hip/hip_bf16.h>

typedef short bfrag8 __attribute__((ext_vector_type(8)));
typedef float f32x4v __attribute__((ext_vector_type(4)));
typedef unsigned short U16;
typedef unsigned int U32;

#define NN 4096
#define DD 128

static __device__ __forceinline__ U16 f2bf(float f){
  union { __hip_bfloat16 b; U16 u; } cv;
  cv.b = __float2bfloat16(f);
  return cv.u;
}

// async global->LDS, 16B per lane: lds dest = wave-uniform base + lane*16,
// global src = per-lane address.
#define GLL16(gsrc, ldst) \
  __builtin_amdgcn_global_load_lds((const __attribute__((address_space(1))) unsigned int*)(gsrc), \
                                   (__attribute__((address_space(3))) unsigned int*)(ldst), 16, 0, 0)

// ---------------- kernel 0a: WT[dp][d] = bf16(W[d][dp]) ----------------
__global__ void k0_wt(const float* __restrict__ W, U16* __restrict__ WT){
  int i = blockIdx.x*256 + threadIdx.x;      // i = d*128 + dp
  int d = i >> 7, dp = i & 127;
  WT[dp*128 + d] = f2bf(W[i]);
}

// ---------------- kernel 0b: pack adj (int 0/1) into bitmask ----------------
// adjb64[row][g] bit l = adj[row][g*64 + l] != 0. Coalesced reads via ballot.
__global__ __launch_bounds__(256) void k0b_pack(const int* __restrict__ adj,
                                                unsigned long long* __restrict__ adjb64){
  const int W = blockIdx.x*4 + (threadIdx.x >> 6);   // wave id, 8192 total
  const int lane = threadIdx.x & 63;
  const int* src = adj + (size_t)W*2048;
  unsigned long long* dst = adjb64 + (size_t)W*32;
  #pragma unroll 4
  for (int p = 0; p < 32; ++p){
    int v = src[p*64 + lane];
    unsigned long long m = __ballot(v != 0);
    if (lane == 0) dst[p] = m;
  }
}

// ---------------- kernel 1: x2 = x*(nw+1)+nb; h_raw = x2@W (MFMA bf16);
// LayerNorm -> h_ln (f32), hTt (bf16 tiled+swizzled), f1/f2 ----------------
__global__ __launch_bounds__(256) void k1_prep(
    const float* __restrict__ x, const U16* __restrict__ WT,
    const float* __restrict__ nw, const float* __restrict__ nb,
    const float* __restrict__ gamma, const float* __restrict__ beta,
    const float* __restrict__ a1, const float* __restrict__ a2,
    float* __restrict__ h_ln, U16* __restrict__ hTt,
    float* __restrict__ f1, float* __restrict__ f2)
{
  __shared__ U16 lds[16384];                 // 32 KB: WT (swizzled), later hb[64][128]
  const int tid = threadIdx.x;
  const int lane = tid & 63, w = tid >> 6;
  const int l15 = lane & 15, grp = lane >> 4;

  #pragma unroll
  for (int q = 0; q < 8; ++q){
    int cid = q*256 + tid;
    int dp = cid >> 4, c = cid & 15;
    *reinterpret_cast<int4*>(lds + dp*128 + ((c*8) ^ ((dp&15)<<3))) =
        *reinterpret_cast<const int4*>(WT + cid*8);
  }
  __syncthreads();

  const int rA = blockIdx.x*64 + w*16 + l15;
  const int nA = rA & 4095;
  const float wgt = nw[nA] + 1.0f, bia = nb[nA];
  const float* xr = x + (size_t)rA*DD;

  f32x4v acc[8] = {};
  #pragma unroll
  for (int ks = 0; ks < 4; ++ks){
    int d8 = ks*32 + grp*8;
    float4 xa = *reinterpret_cast<const float4*>(xr + d8);
    float4 xb = *reinterpret_cast<const float4*>(xr + d8 + 4);
    bfrag8 af;
    af[0] = (short)f2bf(xa.x*wgt + bia);
    af[1] = (short)f2bf(xa.y*wgt + bia);
    af[2] = (short)f2bf(xa.z*wgt + bia);
    af[3] = (short)f2bf(xa.w*wgt + bia);
    af[4] = (short)f2bf(xb.x*wgt + bia);
    af[5] = (short)f2bf(xb.y*wgt + bia);
    af[6] = (short)f2bf(xb.z*wgt + bia);
    af[7] = (short)f2bf(xb.w*wgt + bia);
    #pragma unroll
    for (int nf = 0; nf < 8; ++nf){
      int dp = nf*16 + l15;
      bfrag8 bf = *reinterpret_cast<const bfrag8*>(
          lds + dp*128 + ((((ks*4 + grp)*8)) ^ ((dp&15)<<3)));
      acc[nf] = __builtin_amdgcn_mfma_f32_16x16x32_bf16(af, bf, acc[nf], 0, 0, 0);
    }
  }

  float gc[8], bc[8], c1[8], c2[8];
  #pragma unroll
  for (int nf = 0; nf < 8; ++nf){
    int col = nf*16 + l15;
    gc[nf] = gamma[col]; bc[nf] = beta[col];
    c1[nf] = a1[col];    c2[nf] = a2[col];
  }

  const int rCb = blockIdx.x*64 + w*16 + grp*4;
  #pragma unroll
  for (int r = 0; r < 4; ++r){
    float s = 0.f, qq = 0.f;
    #pragma unroll
    for (int nf = 0; nf < 8; ++nf){ float v = acc[nf][r]; s += v; qq += v*v; }
    #pragma unroll
    for (int m = 1; m < 16; m <<= 1){ s += __shfl_xor(s, m); qq += __shfl_xor(qq, m); }
    float mu = s * 0.0078125f;
    float var = fmaxf(qq*0.0078125f - mu*mu, 0.f);
    float rstd = rsqrtf(var + 1e-5f);
    const int rC = rCb + r;
    float p1 = 0.f, p2 = 0.f;
    #pragma unroll
    for (int nf = 0; nf < 8; ++nf){
      float hn = (acc[nf][r] - mu)*rstd*gc[nf] + bc[nf];
      acc[nf][r] = hn;
      h_ln[(size_t)rC*DD + nf*16 + l15] = hn;
      p1 += hn*c1[nf]; p2 += hn*c2[nf];
    }
    #pragma unroll
    for (int m = 1; m < 16; m <<= 1){ p1 += __shfl_xor(p1, m); p2 += __shfl_xor(p2, m); }
    if (l15 == 0){ f1[rC] = p1; f2[rC] = p2; }
  }

  __syncthreads();   // WT no longer needed; reuse LDS as hb[64 n][128 d]
  #pragma unroll
  for (int r = 0; r < 4; ++r)
    #pragma unroll
    for (int nf = 0; nf < 8; ++nf)
      lds[(w*16 + grp*4 + r)*128 + nf*16 + l15] = f2bf(acc[nf][r]);
  __syncthreads();

  // tiled + inverse-swizzled write: chunk (d,qc) of tile holds
  // h[n = (qc ^ (d&7))*8 + e][d], so k2 can stage linearly (global_load_lds)
  // and read with the XOR swizzle.
  {
    const int r0 = blockIdx.x*64;
    const int tilei = (r0 >> 12)*64 + ((r0 >> 6) & 63);
    U16* dstt = hTt + (size_t)tilei*8192;
    #pragma unroll
    for (int k = 0; k < 4; ++k){
      int cid = tid*4 + k;             // 0..1023
      int d = cid >> 3, qc = cid & 7;
      int nl = (qc ^ (d & 7)) * 8;
      bfrag8 t;
      #pragma unroll
      for (int e = 0; e < 8; ++e)
        t[e] = (short)lds[(nl + e)*128 + d];
      *reinterpret_cast<bfrag8*>(dstt + d*64 + qc*8) = t;
    }
  }
}

// ---------------- kernel 2: fused att-gen + att@h + elu + residual ----------------
// grid 256: block = (batch b, 64 i-rows); 8 waves = 4 tiles(16 rows) x 2 K-halves.
// B-tiles staged via global_load_lds from tiled hTt (coalesced, double-buffered).
__global__ __launch_bounds__(512) void k2_main(
    const U32* __restrict__ adjb, const U16* __restrict__ hTt,
    const float* __restrict__ f1, const float* __restrict__ f2,
    const float* __restrict__ h_ln, float* __restrict__ out)
{
  __shared__ U16 bt[32768];                  // 64 KB: [sbuf 2][kh 2][8192]
  const int tid = threadIdx.x;
  const int lane = tid & 63, w = tid >> 6;
  const int kh = w & 1, tile = w >> 1;
  const int l15 = lane & 15, grp = lane >> 4;
  const int b = blockIdx.x >> 6;
  const int i0 = (blockIdx.x & 63)*64 + tile*16;
  const int row = i0 + l15;

  const float CMASK = 0.2f * -9.0e15f;       // leaky(MASK_VAL), exact
  const float A2C   = 0.04f;                 // leaky∘leaky negative slope

  const float f1v = f1[b*NN + row];
  const float* f2b = f2 + b*NN;
  const U32* arow = adjb + (size_t)row*128;  // 128 u32 words per row
  const U16* hTb = hTt + (size_t)b*64*8192;

  // staging: 8 waves x 4 KB per step (2 tiles of 16 KB: kh0 chunk s, kh1 chunk 32+s)
  const int sg = w >> 2, sq = w & 3;
  const U16* sbase = hTb + (size_t)(sg*32)*8192 + sq*2048 + lane*8;

  // prologue: stage tile s=0 into buf 0
  {
    const U16* gp = sbase;
    int dst = sg*8192 + sq*2048;
    #pragma unroll
    for (int c = 0; c < 4; ++c)
      GLL16(gp + c*512, &bt[dst + c*512]);
  }
  // prologue: regs for s=0
  float4 cfa0, cfb0, cfa1, cfb1; U32 cw0, cw1;
  {
    int j0 = kh*2048 + grp*8;
    cfa0 = *reinterpret_cast<const float4*>(f2b + j0);
    cfb0 = *reinterpret_cast<const float4*>(f2b + j0 + 4);
    cfa1 = *reinterpret_cast<const float4*>(f2b + j0 + 32);
    cfb1 = *reinterpret_cast<const float4*>(f2b + j0 + 36);
    cw0 = arow[kh*64 + 0];
    cw1 = arow[kh*64 + 1];
  }

  f32x4v acc[8] = {};
  __syncthreads();                            // tile 0 staged (compiler drains vmcnt)

  for (int s = 0; s < 32; ++s){
    // issue next tile's staging first (hidden under this iter's compute)
    if (s < 31){
      const U16* gp = sbase + (size_t)(s+1)*8192;
      int dst = (((s+1)&1)*2 + sg)*8192 + sq*2048;
      #pragma unroll
      for (int c = 0; c < 4; ++c)
        GLL16(gp + c*512, &bt[dst + c*512]);
    }
    // prefetch next iter's f2 / adj-bits into regs
    float4 nfa0, nfb0, nfa1, nfb1; U32 nw0, nw1;
    if (s < 31){
      int j0 = kh*2048 + (s+1)*64 + grp*8;
      nfa0 = *reinterpret_cast<const float4*>(f2b + j0);
      nfb0 = *reinterpret_cast<const float4*>(f2b + j0 + 4);
      nfa1 = *reinterpret_cast<const float4*>(f2b + j0 + 32);
      nfb1 = *reinterpret_cast<const float4*>(f2b + j0 + 36);
      int wi = kh*64 + (s+1)*2;
      nw0 = arow[wi]; nw1 = arow[wi+1];
    }

    const int bbase = ((s&1)*2 + kh)*8192;
    // ---- kc = 0 ----
    {
      U32 byt = (cw0 >> (grp*8)) & 0xffu;
      bfrag8 af;
      float sv, uv;
      sv = f1v + cfa0.x; uv = fmaxf(sv, A2C*sv); af[0] = (short)f2bf((byt & 1u)  ? uv : CMASK);
      sv = f1v + cfa0.y; uv = fmaxf(sv, A2C*sv); af[1] = (short)f2bf((byt & 2u)  ? uv : CMASK);
      sv = f1v + cfa0.z; uv = fmaxf(sv, A2C*sv); af[2] = (short)f2bf((byt & 4u)  ? uv : CMASK);
      sv = f1v + cfa0.w; uv = fmaxf(sv, A2C*sv); af[3] = (short)f2bf((byt & 8u)  ? uv : CMASK);
      sv = f1v + cfb0.x; uv = fmaxf(sv, A2C*sv); af[4] = (short)f2bf((byt & 16u) ? uv : CMASK);
      sv = f1v + cfb0.y; uv = fmaxf(sv, A2C*sv); af[5] = (short)f2bf((byt & 32u) ? uv : CMASK);
      sv = f1v + cfb0.z; uv = fmaxf(sv, A2C*sv); af[6] = (short)f2bf((byt & 64u) ? uv : CMASK);
      sv = f1v + cfb0.w; uv = fmaxf(sv, A2C*sv); af[7] = (short)f2bf((byt & 128u)? uv : CMASK);
      const int cr8 = grp*8;
      #pragma unroll
      for (int nf = 0; nf < 8; ++nf){
        int d = nf*16 + l15;
        bfrag8 bf = *reinterpret_cast<const bfrag8*>(
            bt + bbase + d*64 + (cr8 ^ ((d&7)<<3)));
        acc[nf] = __builtin_amdgcn_mfma_f32_16x16x32_bf16(af, bf, acc[nf], 0, 0, 0);
      }
    }
    // ---- kc = 1 ----
    {
      U32 byt = (cw1 >> (grp*8)) & 0xffu;
      bfrag8 af;
      float sv, uv;
      sv = f1v + cfa1.x; uv = fmaxf(sv, A2C*sv); af[0] = (short)f2bf((byt & 1u)  ? uv : CMASK);
      sv = f1v + cfa1.y; uv = fmaxf(sv, A2C*sv); af[1] = (short)f2bf((byt & 2u)  ? uv : CMASK);
      sv = f1v + cfa1.z; uv = fmaxf(sv, A2C*sv); af[2] = (short)f2bf((byt & 4u)  ? uv : CMASK);
      sv = f1v + cfa1.w; uv = fmaxf(sv, A2C*sv); af[3] = (short)f2bf((byt & 8u)  ? uv : CMASK);
      sv = f1v + cfb1.x; uv = fmaxf(sv, A2C*sv); af[4] = (short)f2bf((byt & 16u) ? uv : CMASK);
      sv = f1v + cfb1.y; uv = fmaxf(sv, A2C*sv); af[5] = (short)f2bf((byt & 32u) ? uv : CMASK);
      sv = f1v + cfb1.z; uv = fmaxf(sv, A2C*sv); af[6] = (short)f2bf((byt & 64u) ? uv : CMASK);
      sv = f1v + cfb1.w; uv = fmaxf(sv, A2C*sv); af[7] = (short)f2bf((byt & 128u)? uv : CMASK);
      const int cr8 = 32 + grp*8;
      #pragma unroll
      for (int nf = 0; nf < 8; ++nf){
        int d = nf*16 + l15;
        bfrag8 bf = *reinterpret_cast<const bfrag8*>(
            bt + bbase + d*64 + (cr8 ^ ((d&7)<<3)));
        acc[nf] = __builtin_amdgcn_mfma_f32_16x16x32_bf16(af, bf, acc[nf], 0, 0, 0);
      }
    }

    __syncthreads();   // all waves done with buf[s&1]; next tile drained here
    cfa0 = nfa0; cfb0 = nfb0; cfa1 = nfa1; cfb1 = nfb1; cw0 = nw0; cw1 = nw1;
  }

  // combine K-halves through LDS (reuse bt as f32 scratch), fused epilogue
  float* sc = reinterpret_cast<float*>(bt);   // 8192 floats = 4 tiles x 16 x 128
  if (kh == 1){
    #pragma unroll
    for (int nf = 0; nf < 8; ++nf)
      #pragma unroll
      for (int r = 0; r < 4; ++r)
        sc[tile*2048 + (grp*4 + r)*128 + nf*16 + l15] = acc[nf][r];
  }
  __syncthreads();
  if (kh == 0){
    #pragma unroll
    for (int nf = 0; nf < 8; ++nf)
      #pragma unroll
      for (int r = 0; r < 4; ++r){
        float hp = acc[nf][r] + sc[tile*2048 + (grp*4 + r)*128 + nf*16 + l15];
        float e = hp > 0.f ? hp : __expf(hp) - 1.f;
        size_t o = ((size_t)b*NN + i0 + grp*4 + r)*DD + nf*16 + l15;
        out[o] = e + h_ln[o];
      }
  }
}

extern "C" void kernel_launch(void* const* d_in, const int* in_sizes, int n_in,
                              void* d_out, int out_size, void* d_ws, size_t ws_size,
                              hipStream_t stream) {
  const float* x     = (const float*)d_in[0];
  const int*   adj   = (const int*)  d_in[1];
  const float* W     = (const float*)d_in[2];
  const float* a1    = (const float*)d_in[3];
  const float* a2    = (const float*)d_in[4];
  const float* nw    = (const float*)d_in[5];
  const float* nb    = (const float*)d_in[6];
  const float* gamma = (const float*)d_in[7];
  const float* beta  = (const float*)d_in[8];
  float* out = (float*)d_out;

  char* ws = (char*)d_ws;
  float* h_ln = (float*)(ws);                           // 8 MB
  U16*   hTt  = (U16*)  (ws + 8*1024*1024);             // 4 MB (tiled)
  U16*   WT   = (U16*)  (ws + 12*1024*1024);            // 32 KB
  float* f1   = (float*)(ws + 12*1024*1024 + 64*1024);  // 64 KB
  float* f2   = (float*)(ws + 12*1024*1024 + 128*1024); // 64 KB
  unsigned long long* adjb64 = (unsigned long long*)(ws + 13*1024*1024); // 2 MB

  k0_wt   <<<dim3(64),   dim3(256), 0, stream>>>(W, WT);
  k0b_pack<<<dim3(2048), dim3(256), 0, stream>>>(adj, adjb64);
  k1_prep <<<dim3(256),  dim3(256), 0, stream>>>(x, WT, nw, nb, gamma, beta, a1, a2,
                                                 h_ln, hTt, f1, f2);
  k2_main <<<dim3(256),  dim3(512), 0, stream>>>((const U32*)adjb64, hTt, f1, f2, h_ln, out);
}